// Round 3
// baseline (938.382 us; speedup 1.0000x reference)
//
#include <hip/hip_runtime.h>
#include <stdint.h>

#define NB 64    // scan steps (B)
#define NT 128   // T
#define NF 1024  // F
#define NS 512   // S
#define NM 2048  // M
#define MAXNEW 160
#define SQRT_S 22.627417f  // correctly-rounded f32 of sqrt(512)

// 0.5 - hard_sigmoid(x - s), numpy-identical per-op rounding.
__device__ __forceinline__ float comp_of(float x, float s) {
    float d = __fsub_rn(x, s);
    float t = __fadd_rn(__fmul_rn(0.2f, d), 0.5f);
    t = fminf(fmaxf(t, 0.0f), 1.0f);
    return __fsub_rn(0.5f, t);
}

// order-isomorphic map f32 -> u32 (NaN-free inputs)
__device__ __forceinline__ unsigned fkey(float x) {
    unsigned u = __float_as_uint(x);
    return (u & 0x80000000u) ? ~u : (u | 0x80000000u);
}
// larger key = larger value, ties -> smaller m (np.argmax first-index semantics)
__device__ __forceinline__ unsigned long long packKey(float v, int m) {
    return ((unsigned long long)fkey(v) << 32) | (unsigned)(NM - m);
}

__device__ __forceinline__ unsigned long long reduceMaxKey(
    unsigned long long* redK, int t, unsigned long long local) {
    __syncthreads();            // protect previous redK consumer
    redK[t] = local;
    __syncthreads();
    for (int off = 128; off > 0; off >>= 1) {
        if (t < off) {
            unsigned long long o = redK[t + off];
            if (o > redK[t]) redK[t] = o;
        }
        __syncthreads();
    }
    return redK[0];
}

__global__ void k_zero(int* condS) {
    if (threadIdx.x < NB) condS[threadIdx.x] = 0;
}

// Per (b,f): route-column min/max -> UMS (upd_mem_s), cond_s, upd_idx_s.
// comp is monotone non-increasing in mr (per-op rounding is monotone), so the
// column extremes give max|comp_sp| exactly (interval endpoints are attained);
// cs >= 0 makes max_s of the rounded affine map attained at the column max.
__global__ void k_routes(const float* __restrict__ mr, const float* __restrict__ states,
                         float* __restrict__ UMS, float* __restrict__ updIdxS,
                         int* __restrict__ condS) {
    int b = blockIdx.x;
    int f = blockIdx.y * blockDim.x + threadIdx.x;
    const float* base = mr + (size_t)b * NS * NF + f;
    float mn = base[0], mx = base[0];
    for (int s = 1; s < NS; ++s) {
        float v = base[(size_t)s * NF];
        mn = fminf(mn, v);
        mx = fmaxf(mx, v);
    }
    float sv = states[((size_t)b * NT + NT - 1) * NF + f];
    float compHi = comp_of(mn, sv);   // max comp_sp in this column
    float compLo = comp_of(mx, sv);   // min comp_sp in this column
    float maxabs = fmaxf(compHi, -compLo);      // max |comp_sp|
    float cs   = __fmul_rn(SQRT_S, maxabs);     // comp_s[f]
    float omcs = __fsub_rn(1.0f, cs);
    UMS[b * NF + f] = __fadd_rn(__fmul_rn(mx, cs), __fmul_rn(sv, omcs));

    __shared__ int anyf;
    if (threadIdx.x == 0) anyf = 0;
    __syncthreads();
    if (compHi >= 0.45f) atomicOr(&anyf, 1);
    __syncthreads();
    if (threadIdx.x == 0 && anyf) atomicOr(&condS[b], 1);

    if (f == NF - 1) {
        float mr0l = mr[(size_t)b * NS * NF + NF - 1];  // mr[b, 0, F-1]
        updIdxS[b] = __fadd_rn(__fmul_rn(mr0l, cs), __fmul_rn(sv, omcs));
    }
}

// Per original memory row m: bit b = any_f(comp(mem[m,f], s_b[f]) >= 0.45)
__global__ void k_predorig(const float* __restrict__ memory, const float* __restrict__ states,
                           unsigned long long* __restrict__ predOrig) {
    int m = blockIdx.x, t = threadIdx.x;
    const float4* rowp = (const float4*)(memory + (size_t)m * NF);
    float4 v = rowp[t];
    unsigned long long mask = 0ull;
    for (int b = 0; b < NB; ++b) {
        const float4* sp = (const float4*)(states + ((size_t)b * NT + NT - 1) * NF);
        float4 s = sp[t];
        bool p = (comp_of(v.x, s.x) >= 0.45f) | (comp_of(v.y, s.y) >= 0.45f)
               | (comp_of(v.z, s.z) >= 0.45f) | (comp_of(v.w, s.w) >= 0.45f);
        if (p) mask |= (1ull << b);
    }
    __shared__ unsigned long long sm[256];
    sm[t] = mask;
    __syncthreads();
    for (int off = 128; off > 0; off >>= 1) {
        if (t < off) sm[t] |= sm[t + off];
        __syncthreads();
    }
    if (t == 0) predOrig[m] = sm[0];
}

// Sequential scan, single block. Carry held compressed: rowid[m] -> pool vector.
// Shared rows stay bit-identical, so all exact-equality masks are preserved.
__global__ void __launch_bounds__(256) k_scan(
    const float* __restrict__ states, const float* __restrict__ memory,
    const float* __restrict__ indexIn, const float* __restrict__ UMS,
    const float* __restrict__ updIdxS, const int* __restrict__ condS,
    const unsigned long long* __restrict__ predOrig, float* __restrict__ vecq,
    float* __restrict__ out)
{
    __shared__ uint16_t rowid[NM];
    __shared__ float idxv[NM];
    __shared__ float cqArr[NM];
    __shared__ float memLast[NM];
    __shared__ unsigned long long pOrig[NM];
    __shared__ float sRow[NF];
    __shared__ const float* poolPtr[MAXNEW];
    __shared__ float poolLastN[MAXNEW];
    __shared__ unsigned char liveN[MAXNEW];
    __shared__ unsigned long long redK[256];
    __shared__ int flagI;

    int t = threadIdx.x;
    for (int m = t; m < NM; m += 256) {
        rowid[m] = (uint16_t)m;
        idxv[m] = indexIn[m];
        memLast[m] = memory[(size_t)m * NF + NF - 1];
        pOrig[m] = predOrig[m];
    }
    int nCnt = 0;  // uniform: all increments under uniform conditions

    for (int b = 0; b < NB; ++b) {
        const float* sG = states + ((size_t)b * NT + NT - 1) * NF;
        __syncthreads();
        for (int f = t; f < NF; f += 256) sRow[f] = sG[f];
        __syncthreads();
        float sF = sRow[NF - 1];
        float r = sF;  // state[-1,-1]

        // ---- phase 1: cq[m] = comp_q[m, F-1]; cqmax; first-argmax mi ----
        unsigned long long lk1 = 0;
        for (int m = t; m < NM; m += 256) {
            int p = rowid[m];
            float last = (p < NM) ? memLast[p] : poolLastN[p - NM];
            float c = comp_of(last, sF);
            cqArr[m] = c;
            unsigned long long k = packKey(c, m);
            if (k > lk1) lk1 = k;
        }
        unsigned long long bk1 = reduceMaxKey(redK, t, lk1);
        int mi = NM - (int)(bk1 & 0xFFFFFFFFull);
        float cqmax = cqArr[mi];

        // ---- phase 2: cond_q = any(comp_q >= EPS) over live rows ----
        if (t == 0) flagI = 0;
        for (int i = t; i < nCnt; i += 256) liveN[i] = 0;
        __syncthreads();
        bool lp = false;
        for (int m = t; m < NM; m += 256) {
            int p = rowid[m];
            if (p < NM) { if ((pOrig[p] >> b) & 1ull) lp = true; }
            else liveN[p - NM] = 1;
        }
        if (lp) atomicOr(&flagI, 1);
        __syncthreads();
        for (int i = 0; i < nCnt; ++i) {   // uniform loop
            if (liveN[i]) {
                const float* vp = poolPtr[i];
                bool pp = false;
                for (int f = t; f < NF; f += 256)
                    if (comp_of(vp[f], sRow[f]) >= 0.45f) pp = true;
                if (pp) atomicOr(&flagI, 1);
            }
        }
        __syncthreads();
        bool cond_q = (flagI != 0);

        // ---- phase 3: q-update (non-max rows <- upd_mem_q / upd_idx_q) ----
        if (cond_q) {
            int pmi = rowid[mi];
            float idxmi = idxv[mi];
            const float* src = (pmi < NM) ? (memory + (size_t)pmi * NF) : poolPtr[pmi - NM];
            float c = cqmax;
            float omc = __fsub_rn(1.0f, c);
            float updIdxQ = __fadd_rn(__fmul_rn(idxmi, omc), __fmul_rn(r, c));
            float* dst = vecq + (size_t)b * NF;
            for (int f = t; f < NF; f += 256) {
                float val = __fadd_rn(__fmul_rn(src[f], omc), __fmul_rn(sRow[f], c));
                dst[f] = val;
                if (f == NF - 1) poolLastN[nCnt] = val;
            }
            if (t == 0) poolPtr[nCnt] = dst;
            __syncthreads();
            int nid = NM + nCnt;
            for (int m = t; m < NM; m += 256) {
                if (!(cqArr[m] == cqmax)) { rowid[m] = (uint16_t)nid; idxv[m] = updIdxQ; }
            }
            nCnt++;
        }
        __syncthreads();

        // ---- phase 4: s-update (rows with idx == max(-idx) <- UMS row) ----
        bool cond_s = (condS[b] != 0);
        if (cond_s) {
            unsigned long long lk = 0;
            for (int m = t; m < NM; m += 256) {
                unsigned long long k = packKey(-idxv[m], m);
                if (k > lk) lk = k;
            }
            unsigned long long bk = reduceMaxKey(redK, t, lk);
            int mneg = NM - (int)(bk & 0xFFFFFFFFull);
            float mxneg = -idxv[mneg];
            const float* ums = UMS + (size_t)b * NF;
            float uIdxS = updIdxS[b];
            int sid = NM + nCnt;
            if (t == 0) { poolPtr[nCnt] = ums; poolLastN[nCnt] = ums[NF - 1]; }
            __syncthreads();
            for (int m = t; m < NM; m += 256) {
                if (idxv[m] == mxneg) { rowid[m] = (uint16_t)sid; idxv[m] = uIdxS; }
            }
            nCnt++;
        }
        __syncthreads();

        // ---- phase 5: empty-update (rows with idx == max(-idx) <- s row) ----
        bool cond_e = (!cond_q) && (!cond_s);
        if (cond_e) {
            unsigned long long lk = 0;
            for (int m = t; m < NM; m += 256) {
                unsigned long long k = packKey(-idxv[m], m);
                if (k > lk) lk = k;
            }
            unsigned long long bk = reduceMaxKey(redK, t, lk);
            int mneg = NM - (int)(bk & 0xFFFFFFFFull);
            float mxneg = -idxv[mneg];
            int eid = NM + nCnt;
            if (t == 0) { poolPtr[nCnt] = sG; poolLastN[nCnt] = sF; }
            __syncthreads();
            for (int m = t; m < NM; m += 256) {
                if (idxv[m] == mxneg) { rowid[m] = (uint16_t)eid; idxv[m] = r; }
            }
            nCnt++;
        }
        __syncthreads();

        // ---- phase 6: leader = first-argmax(idx); emit outputs (f32!) ----
        unsigned long long lk6 = 0;
        for (int m = t; m < NM; m += 256) {
            unsigned long long k = packKey(idxv[m], m);
            if (k > lk6) lk6 = k;
        }
        unsigned long long bk6 = reduceMaxKey(redK, t, lk6);
        int li = NM - (int)(bk6 & 0xFFFFFFFFull);
        int pl = rowid[li];
        const float* lvec = (pl < NM) ? (memory + (size_t)pl * NF) : poolPtr[pl - NM];
        float* outT = out + (size_t)b * NF;
        for (int f = t; f < NF; f += 256) outT[f] = lvec[f];
        if (t == 0) out[(size_t)NB * NF + b] = idxv[li];
    }
}

extern "C" void kernel_launch(void* const* d_in, const int* in_sizes, int n_in,
                              void* d_out, int out_size, void* d_ws, size_t ws_size,
                              hipStream_t stream) {
    (void)out_size; (void)ws_size;
    // Defensive: identify inputs by element count (all distinct), fall back to position.
    const float* states  = (const float*)d_in[0];
    const float* mr      = (const float*)d_in[1];
    const float* memory  = (const float*)d_in[2];
    const float* indexIn = (const float*)d_in[3];
    for (int i = 0; i < n_in; ++i) {
        switch (in_sizes[i]) {
            case NB * NT * NF: states  = (const float*)d_in[i]; break;
            case NB * NS * NF: mr      = (const float*)d_in[i]; break;
            case NM * NF:      memory  = (const float*)d_in[i]; break;
            case NM:           indexIn = (const float*)d_in[i]; break;
            default: break;
        }
    }
    float* out = (float*)d_out;  // f32: 64*1024 targets + 64 importances

    char* ws = (char*)d_ws;
    float* UMS      = (float*)ws;                                      // 262144 B
    float* updIdxS  = (float*)(ws + 262144);                           // 256 B
    int*   condS    = (int*)(ws + 262400);                             // 256 B
    unsigned long long* predOrig = (unsigned long long*)(ws + 262656); // 16384 B
    float* vecq     = (float*)(ws + 279040);                           // 262144 B

    k_zero<<<1, 64, 0, stream>>>(condS);
    k_routes<<<dim3(NB, NF / 256), 256, 0, stream>>>(mr, states, UMS, updIdxS, condS);
    k_predorig<<<NM, 256, 0, stream>>>(memory, states, predOrig);
    k_scan<<<1, 256, 0, stream>>>(states, memory, indexIn, UMS, updIdxS, condS, predOrig, vecq, out);
}

// Round 4
// 480.686 us; speedup vs baseline: 1.9522x; 1.9522x over previous
//
#include <hip/hip_runtime.h>
#include <stdint.h>

#define NB 64    // scan steps (B)
#define NT 128   // T
#define NF 1024  // F
#define NS 512   // S
#define NM 2048  // M
#define MAXNEW 160
#define SQRT_S 22.627417f  // correctly-rounded f32 of sqrt(512)

// 0.5 - hard_sigmoid(x - s), numpy-identical per-op rounding.
__device__ __forceinline__ float comp_of(float x, float s) {
    float d = __fsub_rn(x, s);
    float t = __fadd_rn(__fmul_rn(0.2f, d), 0.5f);
    t = fminf(fmaxf(t, 0.0f), 1.0f);
    return __fsub_rn(0.5f, t);
}

// order-isomorphic f32 <-> u32 (NaN-free). Invertible: decode gives bit-exact float.
__device__ __forceinline__ unsigned fkey(float x) {
    unsigned u = __float_as_uint(x);
    return (u & 0x80000000u) ? ~u : (u | 0x80000000u);
}
__device__ __forceinline__ float fkeyInv(unsigned k) {
    return (k & 0x80000000u) ? __uint_as_float(k & 0x7fffffffu) : __uint_as_float(~k);
}
// larger key = larger value, ties -> smaller m (np.argmax first-index semantics)
__device__ __forceinline__ unsigned long long packKey(float v, int m) {
    return ((unsigned long long)fkey(v) << 32) | (unsigned)(NM - m);
}

__global__ void k_zero(int* condS) {
    if (threadIdx.x < NB) condS[threadIdx.x] = 0;
}

// ---- two-stage route reduction (stage 1): partial min/max over a 128-route segment ----
__global__ void k_routes1(const float* __restrict__ mr,
                          float* __restrict__ pMin, float* __restrict__ pMax) {
    int b = blockIdx.x;
    int f = blockIdx.y * 256 + threadIdx.x;
    int seg = blockIdx.z;
    const float* base = mr + (size_t)b * NS * NF + (size_t)seg * (NS / 4) * NF + f;
    float mn0 = base[0],           mx0 = mn0;
    float mn1 = base[NF],          mx1 = mn1;
    float mn2 = base[2 * NF],      mx2 = mn2;
    float mn3 = base[3 * NF],      mx3 = mn3;
    #pragma unroll 4
    for (int s = 4; s < NS / 4; s += 4) {
        float v0 = base[(size_t)s * NF];
        float v1 = base[(size_t)(s + 1) * NF];
        float v2 = base[(size_t)(s + 2) * NF];
        float v3 = base[(size_t)(s + 3) * NF];
        mn0 = fminf(mn0, v0); mx0 = fmaxf(mx0, v0);
        mn1 = fminf(mn1, v1); mx1 = fmaxf(mx1, v1);
        mn2 = fminf(mn2, v2); mx2 = fmaxf(mx2, v2);
        mn3 = fminf(mn3, v3); mx3 = fmaxf(mx3, v3);
    }
    size_t o = ((size_t)seg * NB + b) * NF + f;
    pMin[o] = fminf(fminf(mn0, mn1), fminf(mn2, mn3));
    pMax[o] = fmaxf(fmaxf(mx0, mx1), fmaxf(mx2, mx3));
}

// ---- stage 2: combine segments + epilogue (UMS, cond_s, upd_idx_s) ----
// comp is monotone non-increasing in mr (per-op rounding is monotone), so column
// extremes give max|comp_sp| exactly; cs >= 0 makes max_s attained at column max.
__global__ void k_routes2(const float* __restrict__ pMin, const float* __restrict__ pMax,
                          const float* __restrict__ mr, const float* __restrict__ states,
                          float* __restrict__ UMS, float* __restrict__ updIdxS,
                          int* __restrict__ condS) {
    int b = blockIdx.x;
    int f = blockIdx.y * 256 + threadIdx.x;
    float mn = INFINITY, mx = -INFINITY;
    #pragma unroll
    for (int seg = 0; seg < 4; ++seg) {
        size_t o = ((size_t)seg * NB + b) * NF + f;
        mn = fminf(mn, pMin[o]);
        mx = fmaxf(mx, pMax[o]);
    }
    float sv = states[((size_t)b * NT + NT - 1) * NF + f];
    float compHi = comp_of(mn, sv);
    float compLo = comp_of(mx, sv);
    float maxabs = fmaxf(compHi, -compLo);
    float cs   = __fmul_rn(SQRT_S, maxabs);
    float omcs = __fsub_rn(1.0f, cs);
    UMS[b * NF + f] = __fadd_rn(__fmul_rn(mx, cs), __fmul_rn(sv, omcs));

    __shared__ int anyf;
    if (threadIdx.x == 0) anyf = 0;
    __syncthreads();
    if (compHi >= 0.45f) atomicOr(&anyf, 1);
    __syncthreads();
    if (threadIdx.x == 0 && anyf) atomicOr(&condS[b], 1);

    if (f == NF - 1) {
        float mr0l = mr[(size_t)b * NS * NF + NF - 1];  // mr[b, 0, F-1]
        updIdxS[b] = __fadd_rn(__fmul_rn(mr0l, cs), __fmul_rn(sv, omcs));
    }
}

// ---- fallback single-stage (if ws too small), 4 independent accumulator chains ----
__global__ void k_routes(const float* __restrict__ mr, const float* __restrict__ states,
                         float* __restrict__ UMS, float* __restrict__ updIdxS,
                         int* __restrict__ condS) {
    int b = blockIdx.x;
    int f = blockIdx.y * blockDim.x + threadIdx.x;
    const float* base = mr + (size_t)b * NS * NF + f;
    float mn0 = base[0],      mx0 = mn0;
    float mn1 = base[NF],     mx1 = mn1;
    float mn2 = base[2 * NF], mx2 = mn2;
    float mn3 = base[3 * NF], mx3 = mn3;
    #pragma unroll 4
    for (int s = 4; s < NS; s += 4) {
        float v0 = base[(size_t)s * NF];
        float v1 = base[(size_t)(s + 1) * NF];
        float v2 = base[(size_t)(s + 2) * NF];
        float v3 = base[(size_t)(s + 3) * NF];
        mn0 = fminf(mn0, v0); mx0 = fmaxf(mx0, v0);
        mn1 = fminf(mn1, v1); mx1 = fmaxf(mx1, v1);
        mn2 = fminf(mn2, v2); mx2 = fmaxf(mx2, v2);
        mn3 = fminf(mn3, v3); mx3 = fmaxf(mx3, v3);
    }
    float mn = fminf(fminf(mn0, mn1), fminf(mn2, mn3));
    float mx = fmaxf(fmaxf(mx0, mx1), fmaxf(mx2, mx3));
    float sv = states[((size_t)b * NT + NT - 1) * NF + f];
    float compHi = comp_of(mn, sv);
    float compLo = comp_of(mx, sv);
    float maxabs = fmaxf(compHi, -compLo);
    float cs   = __fmul_rn(SQRT_S, maxabs);
    float omcs = __fsub_rn(1.0f, cs);
    UMS[b * NF + f] = __fadd_rn(__fmul_rn(mx, cs), __fmul_rn(sv, omcs));

    __shared__ int anyf;
    if (threadIdx.x == 0) anyf = 0;
    __syncthreads();
    if (compHi >= 0.45f) atomicOr(&anyf, 1);
    __syncthreads();
    if (threadIdx.x == 0 && anyf) atomicOr(&condS[b], 1);

    if (f == NF - 1) {
        float mr0l = mr[(size_t)b * NS * NF + NF - 1];
        updIdxS[b] = __fadd_rn(__fmul_rn(mr0l, cs), __fmul_rn(sv, omcs));
    }
}

// Per original memory row m: bit b = any_f(comp(mem[m,f], s_b[f]) >= 0.45)
__global__ void k_predorig(const float* __restrict__ memory, const float* __restrict__ states,
                           unsigned long long* __restrict__ predOrig) {
    int m = blockIdx.x, t = threadIdx.x;
    const float4* rowp = (const float4*)(memory + (size_t)m * NF);
    float4 v = rowp[t];
    unsigned long long mask = 0ull;
    for (int b = 0; b < NB; ++b) {
        const float4* sp = (const float4*)(states + ((size_t)b * NT + NT - 1) * NF);
        float4 s = sp[t];
        bool p = (comp_of(v.x, s.x) >= 0.45f) | (comp_of(v.y, s.y) >= 0.45f)
               | (comp_of(v.z, s.z) >= 0.45f) | (comp_of(v.w, s.w) >= 0.45f);
        if (p) mask |= (1ull << b);
    }
    __shared__ unsigned long long sm[256];
    sm[t] = mask;
    __syncthreads();
    for (int off = 128; off > 0; off >>= 1) {
        if (t < off) sm[t] |= sm[t + off];
        __syncthreads();
    }
    if (t == 0) predOrig[m] = sm[0];
}

// Sequential scan, single block. Carry compressed: rowid[m] -> pool vector.
// Shared rows stay bit-identical, so all exact-equality masks are preserved.
// Fixed f-partition: thread t owns f = 4t..4t+3; sRow lives in registers (s4).
__global__ void __launch_bounds__(256) k_scan(
    const float* __restrict__ states, const float* __restrict__ memory,
    const float* __restrict__ indexIn, const float* __restrict__ UMS,
    const float* __restrict__ updIdxS, const int* __restrict__ condS,
    const unsigned long long* __restrict__ predOrig, float* __restrict__ vecq,
    float* __restrict__ out)
{
    __shared__ uint16_t rowid[NM];
    __shared__ float idxv[NM];
    __shared__ float cqArr[NM];
    __shared__ float memLast[NM];
    __shared__ unsigned long long pOrig[NM];
    __shared__ const float* poolPtr[MAXNEW];
    __shared__ float poolLastN[MAXNEW];
    __shared__ unsigned char liveN[MAXNEW];
    __shared__ unsigned long long redW[4];
    __shared__ float sFsh;
    __shared__ int flagQ;

    int t = threadIdx.x;
    int lane = t & 63, wid = t >> 6;

    for (int m = t; m < NM; m += 256) {
        rowid[m] = (uint16_t)m;
        idxv[m] = indexIn[m];
        memLast[m] = memory[(size_t)m * NF + NF - 1];
        pOrig[m] = predOrig[m];
    }
    int nCnt = 0;  // uniform: all increments under uniform conditions

    for (int b = 0; b < NB; ++b) {
        // prefetch everything the step needs up front
        const float* sG = states + ((size_t)b * NT + NT - 1) * NF;
        float4 s4 = *(const float4*)(sG + 4 * t);
        float4 u4 = *(const float4*)(UMS + (size_t)b * NF + 4 * t);
        int   cS    = condS[b];
        float uIdxS = updIdxS[b];

        __syncthreads();                 // prev-step LDS consumers done
        if (t == 0) flagQ = 0;
        for (int i = t; i < nCnt; i += 256) liveN[i] = 0;
        if (t == 255) sFsh = s4.w;       // broadcast s[F-1]
        __syncthreads();
        float sF = sFsh;
        float r = sF;                    // state[-1,-1]

        // ---- phase 1: cq per row, max+first-argmax; orig-row cond_q bits ----
        unsigned long long lk1 = 0; bool lp = false;
        #pragma unroll
        for (int k = 0; k < NM / 256; ++k) {
            int m = t + 256 * k;
            int p = rowid[m];
            float last;
            if (p < NM) {
                last = memLast[p];
                if ((pOrig[p] >> b) & 1ull) lp = true;
            } else {
                last = poolLastN[p - NM];
                liveN[p - NM] = 1;
            }
            float c = comp_of(last, sF);
            cqArr[m] = c;
            unsigned long long kk = packKey(c, m);
            if (kk > lk1) lk1 = kk;
        }
        #pragma unroll
        for (int off = 32; off > 0; off >>= 1) {
            unsigned long long o = __shfl_down(lk1, off, 64);
            if (o > lk1) lk1 = o;
        }
        if (lane == 0) redW[wid] = lk1;
        if (lp) atomicOr(&flagQ, 1);
        __syncthreads();
        unsigned long long bk1 = redW[0];
        #pragma unroll
        for (int w = 1; w < 4; ++w) if (redW[w] > bk1) bk1 = redW[w];
        int   mi    = NM - (int)(bk1 & 0xffffffffull);
        float cqmax = fkeyInv((unsigned)(bk1 >> 32));   // bit-exact cqArr[mi]
        bool condQorig = (flagQ != 0);

        // ---- phase 2: pool-vector part of cond_q (skipped if bits already hit) ----
        if (!condQorig) {
            bool pp = false;
            for (int i = 0; i < nCnt; ++i) {   // uniform loop
                if (liveN[i]) {
                    float4 v = *(const float4*)(poolPtr[i] + 4 * t);
                    if (comp_of(v.x, s4.x) >= 0.45f || comp_of(v.y, s4.y) >= 0.45f ||
                        comp_of(v.z, s4.z) >= 0.45f || comp_of(v.w, s4.w) >= 0.45f) pp = true;
                }
            }
            if (pp) atomicOr(&flagQ, 1);
            __syncthreads();
        }
        bool cond_q = (flagQ != 0);

        // ---- phase 3: q-update (non-max rows <- upd_mem_q / upd_idx_q) ----
        if (cond_q) {
            int pmi = rowid[mi];
            float idxmi = idxv[mi];              // mi is a max row: never written below
            const float* src = (pmi < NM) ? (memory + (size_t)pmi * NF) : poolPtr[pmi - NM];
            float4 v = *(const float4*)(src + 4 * t);
            float c = cqmax, omc = __fsub_rn(1.0f, c);
            float updIdxQ = __fadd_rn(__fmul_rn(idxmi, omc), __fmul_rn(r, c));
            float4 o;
            o.x = __fadd_rn(__fmul_rn(v.x, omc), __fmul_rn(s4.x, c));
            o.y = __fadd_rn(__fmul_rn(v.y, omc), __fmul_rn(s4.y, c));
            o.z = __fadd_rn(__fmul_rn(v.z, omc), __fmul_rn(s4.z, c));
            o.w = __fadd_rn(__fmul_rn(v.w, omc), __fmul_rn(s4.w, c));
            *(float4*)(vecq + (size_t)b * NF + 4 * t) = o;
            if (t == 255) poolLastN[nCnt] = o.w;
            if (t == 0)   poolPtr[nCnt] = vecq + (size_t)b * NF;
            int nid = NM + nCnt;
            #pragma unroll
            for (int k = 0; k < NM / 256; ++k) {
                int m = t + 256 * k;
                if (!(cqArr[m] == cqmax)) { rowid[m] = (uint16_t)nid; idxv[m] = updIdxQ; }
            }
            nCnt++;
        }
        __syncthreads();

        // ---- phase 4/5 merged: s-update or empty-update (mutually exclusive) ----
        bool cond_s = (cS != 0);
        bool cond_e = (!cond_q) && (!cond_s);
        if (cond_s || cond_e) {
            unsigned long long lk2 = 0;
            #pragma unroll
            for (int k = 0; k < NM / 256; ++k) {
                int m = t + 256 * k;
                unsigned long long kk = packKey(-idxv[m], m);
                if (kk > lk2) lk2 = kk;
            }
            #pragma unroll
            for (int off = 32; off > 0; off >>= 1) {
                unsigned long long o = __shfl_down(lk2, off, 64);
                if (o > lk2) lk2 = o;
            }
            if (lane == 0) redW[wid] = lk2;
            __syncthreads();
            unsigned long long bk2 = redW[0];
            #pragma unroll
            for (int w = 1; w < 4; ++w) if (redW[w] > bk2) bk2 = redW[w];
            float mxneg = fkeyInv((unsigned)(bk2 >> 32));   // bit-exact max(-idx)
            float newIdx = cond_s ? uIdxS : r;
            if (t == 0)   poolPtr[nCnt] = cond_s ? (UMS + (size_t)b * NF) : sG;
            if (t == 255) poolLastN[nCnt] = cond_s ? u4.w : s4.w;
            int sid = NM + nCnt;
            #pragma unroll
            for (int k = 0; k < NM / 256; ++k) {
                int m = t + 256 * k;
                if (idxv[m] == mxneg) { rowid[m] = (uint16_t)sid; idxv[m] = newIdx; }
            }
            nCnt++;
        }
        __syncthreads();

        // ---- phase 6: leader = first-argmax(idx); emit outputs ----
        unsigned long long lk3 = 0;
        #pragma unroll
        for (int k = 0; k < NM / 256; ++k) {
            int m = t + 256 * k;
            unsigned long long kk = packKey(idxv[m], m);
            if (kk > lk3) lk3 = kk;
        }
        #pragma unroll
        for (int off = 32; off > 0; off >>= 1) {
            unsigned long long o = __shfl_down(lk3, off, 64);
            if (o > lk3) lk3 = o;
        }
        if (lane == 0) redW[wid] = lk3;
        __syncthreads();
        unsigned long long bk3 = redW[0];
        #pragma unroll
        for (int w = 1; w < 4; ++w) if (redW[w] > bk3) bk3 = redW[w];
        int   li   = NM - (int)(bk3 & 0xffffffffull);
        float lidx = fkeyInv((unsigned)(bk3 >> 32));   // bit-exact idxv[li]
        int pl = rowid[li];
        const float* lvec = (pl < NM) ? (memory + (size_t)pl * NF) : poolPtr[pl - NM];
        float4 o4 = *(const float4*)(lvec + 4 * t);
        *(float4*)(out + (size_t)b * NF + 4 * t) = o4;
        if (t == 0) out[(size_t)NB * NF + b] = lidx;
    }
}

extern "C" void kernel_launch(void* const* d_in, const int* in_sizes, int n_in,
                              void* d_out, int out_size, void* d_ws, size_t ws_size,
                              hipStream_t stream) {
    (void)out_size;
    const float* states  = (const float*)d_in[0];
    const float* mr      = (const float*)d_in[1];
    const float* memory  = (const float*)d_in[2];
    const float* indexIn = (const float*)d_in[3];
    for (int i = 0; i < n_in; ++i) {
        switch (in_sizes[i]) {
            case NB * NT * NF: states  = (const float*)d_in[i]; break;
            case NB * NS * NF: mr      = (const float*)d_in[i]; break;
            case NM * NF:      memory  = (const float*)d_in[i]; break;
            case NM:           indexIn = (const float*)d_in[i]; break;
            default: break;
        }
    }
    float* out = (float*)d_out;  // f32: 64*1024 targets + 64 importances

    char* ws = (char*)d_ws;
    float* UMS      = (float*)ws;                                      // 262144 B
    float* updIdxS  = (float*)(ws + 262144);                           // 256 B
    int*   condS    = (int*)(ws + 262400);                             // 256 B
    unsigned long long* predOrig = (unsigned long long*)(ws + 262656); // 16384 B
    float* vecq     = (float*)(ws + 279040);                           // 262144 B -> 541184
    float* pMin     = (float*)(ws + 541184);                           // 262144 B -> 803328
    float* pMax     = (float*)(ws + 803328);                           // 262144 B -> 1065472
    bool twoStage = (ws_size >= 1065472);

    k_zero<<<1, 64, 0, stream>>>(condS);
    if (twoStage) {
        k_routes1<<<dim3(NB, 4, 4), 256, 0, stream>>>(mr, pMin, pMax);
        k_routes2<<<dim3(NB, 4), 256, 0, stream>>>(pMin, pMax, mr, states, UMS, updIdxS, condS);
    } else {
        k_routes<<<dim3(NB, 4), 256, 0, stream>>>(mr, states, UMS, updIdxS, condS);
    }
    k_predorig<<<NM, 256, 0, stream>>>(memory, states, predOrig);
    k_scan<<<1, 256, 0, stream>>>(states, memory, indexIn, UMS, updIdxS, condS, predOrig, vecq, out);
}